// Round 11
// baseline (57.348 us; speedup 1.0000x reference)
//
#include <hip/hip_runtime.h>
#include <hip/hip_bf16.h>

#define B_    64
#define N_    512
#define K_    16
#define D_    128
#define NPBLK 128               // nodes per block
#define GG    ((B_*N_)/NPBLK)   // 256 blocks, 1 per CU

typedef float f32x4  __attribute__((ext_vector_type(4)));
typedef short bf16x8 __attribute__((ext_vector_type(8)));

static __device__ __forceinline__ short f2bf(float x) {
    union { float f; unsigned u; } v; v.f = x;
    unsigned r = v.u + 0x7fffu + ((v.u >> 16) & 1u);  // RNE
    return (short)(r >> 16);
}
static __device__ __forceinline__ float bf2f(short h) {
    return __uint_as_float(((unsigned)(unsigned short)h) << 16);
}
static __device__ __forceinline__ float fast_tanh(float x) {
    float e = __expf(2.f * x);
    return 1.f - 2.f * __builtin_amdgcn_rcpf(e + 1.f);
}

// ---------------------------------------------------------------------------
// pack: blocks 0..23 -> Bp1e (enc1), Bpw (weight/16), Bp2 (enc2/16), K=128
// frag order; blocks 24..55 -> zero d_out.
// frag elem j of lane l, tile nt, step ks = M[ks*32+(l>>4)*8+j][nt*16+(l&15)]
// ---------------------------------------------------------------------------
__global__ __launch_bounds__(256) void pack(const float* __restrict__ enc1,
                                            const float* __restrict__ wgt,
                                            const float* __restrict__ enc2,
                                            short* __restrict__ Bp1e,
                                            short* __restrict__ Bpw,
                                            short* __restrict__ Bp2,
                                            float* __restrict__ out) {
    const int blk = blockIdx.x, t = threadIdx.x;
    if (blk >= 24) { out[(blk - 24) * 256 + t] = 0.f; return; }
    const int ptid = blk * 256 + t;          // 0..6143
    const int m3 = ptid >> 11;               // 0 enc1, 1 weight/16, 2 enc2/16
    const int r = ptid & 2047;
    const int ks = r >> 9, nt = (r >> 6) & 7, l = r & 63;
    const int k0 = ks * 32 + (l >> 4) * 8;
    const int col = nt * 16 + (l & 15);
    const float* src = (m3 == 0) ? enc1 : (m3 == 1) ? wgt : enc2;
    const float scale = (m3 == 0) ? 1.0f : 0.0625f;
    short* dst = (m3 == 0) ? Bp1e : (m3 == 1) ? Bpw : Bp2;
    short o8[8];
#pragma unroll
    for (int j = 0; j < 8; ++j) o8[j] = f2bf(src[(k0 + j) * 128 + col] * scale);
    *(int4*)&dst[(size_t)r * 8] = *(int4*)o8;
}

// 256 blocks, 4 per batch. XCD k (hw%8==k) <- batches [8k,8k+8).
static __device__ __forceinline__ int swz_blk() {
    const int hw = blockIdx.x;
    return ((hw & 7) << 5) + (hw >> 3);
}

// row-swizzled LDS byte address for staged [512][128] bf16 matrix
static __device__ __forceinline__ int lds_addr(int row, int colb) {
    return (row * 256 + colb) ^ ((row & 7) << 4);
}

// ---------------------------------------------------------------------------
// g1: stage lib batch-slice bf16 in LDS; base = word@enc1 + sum_nb lib[idx]@ (W/16)
//     via K-extended MFMA (neighbor sum inside f32 accumulator).
//     Writes baseh, t1 = tanh(base) (bf16).
// 256 blocks x 512 threads; block = 128 nodes; wave = 16-node tile, all 8 nt.
// ---------------------------------------------------------------------------
__global__ __launch_bounds__(512, 2) void g1(const float* __restrict__ word,
                                             const int* __restrict__ nbrL,
                                             const float* __restrict__ lib,
                                             const short* __restrict__ Bp1e,
                                             const short* __restrict__ Bpw,
                                             short* __restrict__ baseh,
                                             short* __restrict__ t1g) {
    extern __shared__ char smem[];
    short* sM  = (short*)smem;                    // [512][128] bf16, swizzled
    int*  sIdx = (int*)(smem + 131072);           // [128][16]
    const int tid = threadIdx.x;
    const int logical = swz_blk();
    const int b = logical >> 2;
    const int node0 = (logical & 3) * NPBLK;      // within batch
    const int gnode0 = b * N_ + node0;            // global node row

    // stage lib (fp32 -> bf16, swizzled)
    const float* libB = lib + (size_t)b * N_ * D_;
#pragma unroll 4
    for (int it = 0; it < 32; ++it) {
        const int i = it * 2048 + tid * 4;        // linear elem in [512*128]
        float4 v = *(const float4*)&libB[i];
        short4 s; s.x = f2bf(v.x); s.y = f2bf(v.y); s.z = f2bf(v.z); s.w = f2bf(v.w);
        *(short4*)(smem + lds_addr(i >> 7, (i & 127) * 2)) = s;
    }
    *(int4*)&sIdx[tid * 4] = *(const int4*)&nbrL[(size_t)gnode0 * 16 + tid * 4];
    __syncthreads();

    const int w = tid >> 6, l = tid & 63;
    const int nrow = w * 16 + (l & 15);           // my A-row (node within block)
    int nidx[16];
#pragma unroll
    for (int nb = 0; nb < 16; ++nb) nidx[nb] = sIdx[nrow * 16 + nb];

    f32x4 acc[8];
#pragma unroll
    for (int nt = 0; nt < 8; ++nt) acc[nt] = (f32x4)0.f;

    // B fragments (32 = 4 ks x 8 nt), kept in registers
    bf16x8 bf[32];
#pragma unroll
    for (int q = 0; q < 32; ++q) bf[q] = *(const bf16x8*)&Bp1e[(size_t)(q * 64 + l) * 8];

    // word pass: K=128, a-frags straight from global fp32
    {
        const float* wr = word + (size_t)(gnode0 + nrow) * D_ + (l >> 4) * 8;
#pragma unroll
        for (int ks = 0; ks < 4; ++ks) {
            float4 a0 = *(const float4*)&wr[ks * 32];
            float4 a1 = *(const float4*)&wr[ks * 32 + 4];
            short af[8];
            af[0]=f2bf(a0.x); af[1]=f2bf(a0.y); af[2]=f2bf(a0.z); af[3]=f2bf(a0.w);
            af[4]=f2bf(a1.x); af[5]=f2bf(a1.y); af[6]=f2bf(a1.z); af[7]=f2bf(a1.w);
            bf16x8 av = *(bf16x8*)af;
#pragma unroll
            for (int nt = 0; nt < 8; ++nt)
                acc[nt] = __builtin_amdgcn_mfma_f32_16x16x32_bf16(av, bf[ks * 8 + nt], acc[nt], 0, 0, 0);
        }
    }

    // swap to weight/16 fragments
#pragma unroll
    for (int q = 0; q < 32; ++q) bf[q] = *(const bf16x8*)&Bpw[(size_t)(q * 64 + l) * 8];

    // neighbor pass: K=16*128, a-frags from swizzled LDS (no unpack!)
    const int laneoff = (l >> 4) * 16;
#pragma unroll
    for (int nb = 0; nb < 16; ++nb) {
        const int rbase = nidx[nb] * 256 + laneoff;
        const int swz = (nidx[nb] & 7) << 4;
#pragma unroll
        for (int ksq = 0; ksq < 4; ++ksq) {
            bf16x8 av = *(const bf16x8*)(smem + ((rbase + ksq * 64) ^ swz));
#pragma unroll
            for (int nt = 0; nt < 8; ++nt)
                acc[nt] = __builtin_amdgcn_mfma_f32_16x16x32_bf16(av, bf[ksq * 8 + nt], acc[nt], 0, 0, 0);
        }
    }

    // epilogue: base, t1
    const int r0 = w * 16 + (l >> 4) * 4;
    const int cl = l & 15;
#pragma unroll
    for (int nt = 0; nt < 8; ++nt) {
        const int col = nt * 16 + cl;
#pragma unroll
        for (int r = 0; r < 4; ++r) {
            size_t o = (size_t)(gnode0 + r0 + r) * D_ + col;
            float v = acc[nt][r];
            baseh[o] = f2bf(v);
            t1g[o]   = f2bf(fast_tanh(v));
        }
    }
}

// ---------------------------------------------------------------------------
// g2: stage t1 batch-slice in LDS; acc = sum_nb t1[idx] @ (enc2/16) via MFMA;
//     t2 = tanh(base + acc); out[b] += (sum mask*t2) @ w2.
// ---------------------------------------------------------------------------
__global__ __launch_bounds__(512, 2) void g2(const short* __restrict__ t1g,
                                             const int* __restrict__ nbr,
                                             const short* __restrict__ Bp2,
                                             const short* __restrict__ baseh,
                                             const float* __restrict__ mask,
                                             const float* __restrict__ w2,
                                             float* __restrict__ out) {
    extern __shared__ char smem[];
    short* sM   = (short*)smem;                   // [512][128] bf16, swizzled
    int*  sIdx  = (int*)(smem + 131072);          // [128][16]
    float* pred = (float*)(smem + 131072 + 8192); // [8][128]
    float* ptot = (float*)(smem + 131072 + 8192 + 4096); // [128]
    float* smask= (float*)(smem + 131072 + 8192 + 4096 + 512); // [128]
    const int tid = threadIdx.x;
    const int logical = swz_blk();
    const int b = logical >> 2;
    const int node0 = (logical & 3) * NPBLK;
    const int gnode0 = b * N_ + node0;

    // stage t1 (bf16 passthrough, swizzled)
    const short* tB = t1g + (size_t)b * N_ * D_;
#pragma unroll 4
    for (int it = 0; it < 16; ++it) {
        const int i = it * 4096 + tid * 8;        // elem index
        int4 v = *(const int4*)&tB[i];
        *(int4*)(smem + lds_addr(i >> 7, (i & 127) * 2)) = v;
    }
    *(int4*)&sIdx[tid * 4] = *(const int4*)&nbr[(size_t)gnode0 * 16 + tid * 4];
    if (tid < 128) smask[tid] = mask[gnode0 + tid];
    __syncthreads();

    const int w = tid >> 6, l = tid & 63;
    const int nrow = w * 16 + (l & 15);
    int nidx[16];
#pragma unroll
    for (int nb = 0; nb < 16; ++nb) nidx[nb] = sIdx[nrow * 16 + nb];

    f32x4 acc[8];
#pragma unroll
    for (int nt = 0; nt < 8; ++nt) acc[nt] = (f32x4)0.f;

    bf16x8 bf[32];
#pragma unroll
    for (int q = 0; q < 32; ++q) bf[q] = *(const bf16x8*)&Bp2[(size_t)(q * 64 + l) * 8];

    const int laneoff = (l >> 4) * 16;
#pragma unroll
    for (int nb = 0; nb < 16; ++nb) {
        const int rbase = nidx[nb] * 256 + laneoff;
        const int swz = (nidx[nb] & 7) << 4;
#pragma unroll
        for (int ksq = 0; ksq < 4; ++ksq) {
            bf16x8 av = *(const bf16x8*)(smem + ((rbase + ksq * 64) ^ swz));
#pragma unroll
            for (int nt = 0; nt < 8; ++nt)
                acc[nt] = __builtin_amdgcn_mfma_f32_16x16x32_bf16(av, bf[ksq * 8 + nt], acc[nt], 0, 0, 0);
        }
    }

    // epilogue: tanh(base+acc), mask-weighted column sums
    const int r0 = w * 16 + (l >> 4) * 4;
    const int cl = l & 15;
#pragma unroll
    for (int nt = 0; nt < 8; ++nt) {
        const int col = nt * 16 + cl;
        float s = 0.f;
#pragma unroll
        for (int r = 0; r < 4; ++r) {
            size_t o = (size_t)(gnode0 + r0 + r) * D_ + col;
            float v = fast_tanh(bf2f(baseh[o]) + acc[nt][r]);
            s += v * smask[r0 + r];
        }
        s += __shfl_xor(s, 16);
        s += __shfl_xor(s, 32);
        if (l < 16) pred[w * 128 + col] = s;
    }
    __syncthreads();
    if (tid < 128) {
        float tot = 0.f;
#pragma unroll
        for (int i = 0; i < 8; ++i) tot += pred[i * 128 + tid];
        ptot[tid] = tot;
    }
    __syncthreads();
    if (tid < 128) {
        float a2 = 0.f;
#pragma unroll 4
        for (int f = 0; f < 128; ++f) a2 += ptot[f] * w2[f * 128 + tid];
        atomicAdd(&out[b * 128 + tid], a2);
    }
}

extern "C" void kernel_launch(void* const* d_in, const int* in_sizes, int n_in,
                              void* d_out, int out_size, void* d_ws, size_t ws_size,
                              hipStream_t stream) {
    const float* word_embs   = (const float*)d_in[0];
    const int*   neibors     = (const int*)d_in[1];
    const float* lib_embs    = (const float*)d_in[2];
    const int*   neibors_lib = (const int*)d_in[3];
    const float* mask        = (const float*)d_in[4];
    const float* weight      = (const float*)d_in[5];
    const float* weight2     = (const float*)d_in[6];
    const float* enc_w1      = (const float*)d_in[7];
    const float* enc_w2      = (const float*)d_in[8];
    float* out = (float*)d_out;

    char* ws = (char*)d_ws;
    short* baseh = (short*)(ws);                        // 8 MB
    short* t1g   = (short*)(ws + (1u << 23));           // 8 MB
    short* Bp1e  = (short*)(ws + (2u << 23));           // 32 KB
    short* Bpw   = (short*)(ws + (2u << 23) + 32768);   // 32 KB
    short* Bp2   = (short*)(ws + (2u << 23) + 65536);   // 32 KB

    static int attr_done = 0;
    // Allow >64KB dynamic LDS (gfx950 supports 160 KiB/WG). Host-side attr set;
    // idempotent and capture-safe.
    hipFuncSetAttribute((const void*)g1, hipFuncAttributeMaxDynamicSharedMemorySize, 139264);
    hipFuncSetAttribute((const void*)g2, hipFuncAttributeMaxDynamicSharedMemorySize, 144896);
    (void)attr_done;

    pack<<<56, 256, 0, stream>>>(enc_w1, weight, enc_w2, Bp1e, Bpw, Bp2, out);
    g1<<<GG, 512, 139264, stream>>>(word_embs, neibors_lib, lib_embs, Bp1e, Bpw, baseh, t1g);
    g2<<<GG, 512, 144896, stream>>>(t1g, neibors, Bp2, baseh, mask, weight2, out);
}

// Round 12
// 55.746 us; speedup vs baseline: 1.0287x; 1.0287x over previous
//
#include <hip/hip_runtime.h>
#include <hip/hip_bf16.h>

#define B_    64
#define N_    512
#define D_    128

typedef float f32x4  __attribute__((ext_vector_type(4)));
typedef short bf16x8 __attribute__((ext_vector_type(8)));

static __device__ __forceinline__ short f2bf(float x) {
    union { float f; unsigned u; } v; v.f = x;
    unsigned r = v.u + 0x7fffu + ((v.u >> 16) & 1u);  // RNE
    return (short)(r >> 16);
}
static __device__ __forceinline__ float bfbits2f(unsigned hi_bits) {
    return __uint_as_float(hi_bits);
}
static __device__ __forceinline__ float bf2f(short h) {
    return __uint_as_float(((unsigned)(unsigned short)h) << 16);
}
static __device__ __forceinline__ float fast_tanh(float x) {
    float e = __expf(2.f * x);
    return 1.f - 2.f * __builtin_amdgcn_rcpf(e + 1.f);
}
// packed 2xf32 add in one VALU instruction
static __device__ __forceinline__ void pk_add(float2& acc, float x, float y) {
    float2 v; v.x = x; v.y = y;
    asm("v_pk_add_f32 %0, %1, %0" : "+v"(acc) : "v"(v));
}

// ---------------------------------------------------------------------------
// pack: blocks 0..23 -> Bp1e (enc1), Bpw (weight/16), Bp2 (enc2/16), K=128
// frag order; blocks 24..55 -> zero d_out.
// frag elem j of lane l, tile nt, step ks = M[ks*32+(l>>4)*8+j][nt*16+(l&15)]
// ---------------------------------------------------------------------------
__global__ __launch_bounds__(256) void pack(const float* __restrict__ enc1,
                                            const float* __restrict__ wgt,
                                            const float* __restrict__ enc2,
                                            short* __restrict__ Bp1e,
                                            short* __restrict__ Bpw,
                                            short* __restrict__ Bp2,
                                            float* __restrict__ out) {
    const int blk = blockIdx.x, t = threadIdx.x;
    if (blk >= 24) { out[(blk - 24) * 256 + t] = 0.f; return; }
    const int ptid = blk * 256 + t;          // 0..6143
    const int m3 = ptid >> 11;               // 0 enc1, 1 weight/16, 2 enc2/16
    const int r = ptid & 2047;
    const int ks = r >> 9, nt = (r >> 6) & 7, l = r & 63;
    const int k0 = ks * 32 + (l >> 4) * 8;
    const int col = nt * 16 + (l & 15);
    const float* src = (m3 == 0) ? enc1 : (m3 == 1) ? wgt : enc2;
    const float scale = (m3 == 0) ? 1.0f : 0.0625f;
    short* dst = (m3 == 0) ? Bp1e : (m3 == 1) ? Bpw : Bp2;
    short o8[8];
#pragma unroll
    for (int j = 0; j < 8; ++j) o8[j] = f2bf(src[(k0 + j) * 128 + col] * scale);
    *(int4*)&dst[(size_t)r * 8] = *(int4*)o8;
}

// 256 blocks, 4 per batch. XCD k (hw%8==k) <- batches [8k,8k+8).
static __device__ __forceinline__ int swz_blk() {
    const int hw = blockIdx.x;
    return ((hw & 7) << 5) + (hw >> 3);
}

// swizzled byte address into staged [512][256B] bf16 slice
static __device__ __forceinline__ int s_addr(int row, int colb) {
    return (row * 256 + colb) ^ ((row & 7) << 4);
}

#define LDA1 264   // K=256 A-tile row stride (shorts), +8 pad
#define LDA2 136   // K=128 A-tile row stride (shorts), +8 pad
#define T1OFF 69632  // byte offset of t1 tile region (> 128*264*2 = 67584)

// ---------------------------------------------------------------------------
// g1: per block (1/CU): stage lib batch-slice bf16 in LDS (swizzled);
//     agg via wide LDS reads + pk_add; base = [word|agg] @ [enc1;wgt/16] MFMA;
//     t1=tanh(base) -> LDS; u = t1 @ (enc2/16) MFMA. Writes baseh, u (bf16).
// ---------------------------------------------------------------------------
__global__ __launch_bounds__(512, 2) void g1(const float* __restrict__ word,
                                             const int* __restrict__ nbrL,
                                             const float* __restrict__ lib,
                                             const short* __restrict__ Bp1e,
                                             const short* __restrict__ Bpw,
                                             const short* __restrict__ Bp2,
                                             short* __restrict__ baseh,
                                             short* __restrict__ u) {
    extern __shared__ char smem[];
    const int tid = threadIdx.x;
    const int logical = swz_blk();
    const int b = logical >> 2;
    const int node0 = (logical & 3) * 128;
    const int gnode0 = b * N_ + node0;

    // Phase 0: stage lib (fp32 -> bf16, swizzled)
    const float* libB = lib + (size_t)b * N_ * D_;
#pragma unroll 4
    for (int it = 0; it < 16; ++it) {
        const int i = it * 4096 + tid * 8;
        float4 v0 = *(const float4*)&libB[i];
        float4 v1 = *(const float4*)&libB[i + 4];
        short o8[8];
        o8[0]=f2bf(v0.x); o8[1]=f2bf(v0.y); o8[2]=f2bf(v0.z); o8[3]=f2bf(v0.w);
        o8[4]=f2bf(v1.x); o8[5]=f2bf(v1.y); o8[6]=f2bf(v1.z); o8[7]=f2bf(v1.w);
        *(int4*)(smem + s_addr(i >> 7, (i & 127) * 2)) = *(int4*)o8;
    }
    __syncthreads();

    // Phase 1: agg (thread owns row=tid>>2, cols cc*32..+32)
    const int row = tid >> 2, cc = tid & 3;
    int idxv[16];
#pragma unroll
    for (int q = 0; q < 4; ++q)
        *(int4*)&idxv[q * 4] = *(const int4*)&nbrL[(size_t)(gnode0 + row) * 16 + q * 4];
    float2 ac[16];
#pragma unroll
    for (int q = 0; q < 16; ++q) { ac[q].x = 0.f; ac[q].y = 0.f; }
#pragma unroll
    for (int nb = 0; nb < 16; ++nb) {
        const int rr = idxv[nb];
        const int sbase = rr * 256 + cc * 64;
        const int sw = (rr & 7) << 4;
#pragma unroll
        for (int j = 0; j < 4; ++j) {
            int4 d = *(const int4*)(smem + ((sbase + j * 16) ^ sw));
            const unsigned* du = (const unsigned*)&d;
#pragma unroll
            for (int q = 0; q < 4; ++q) {
                pk_add(ac[j * 4 + q], bfbits2f(du[q] << 16), bfbits2f(du[q] & 0xffff0000u));
            }
        }
    }
    __syncthreads();   // staged lib dead

    // Phase 2: build sA = [word | aggsum] (K=256, row stride LDA1)
    short* sA = (short*)smem;
    {
        const float* wr = word + (size_t)(gnode0 + row) * D_ + cc * 32;
#pragma unroll
        for (int q = 0; q < 4; ++q) {
            float4 v0 = *(const float4*)&wr[q * 8];
            float4 v1 = *(const float4*)&wr[q * 8 + 4];
            short o8[8];
            o8[0]=f2bf(v0.x); o8[1]=f2bf(v0.y); o8[2]=f2bf(v0.z); o8[3]=f2bf(v0.w);
            o8[4]=f2bf(v1.x); o8[5]=f2bf(v1.y); o8[6]=f2bf(v1.z); o8[7]=f2bf(v1.w);
            *(int4*)&sA[row * LDA1 + cc * 32 + q * 8] = *(int4*)o8;
        }
#pragma unroll
        for (int q = 0; q < 4; ++q) {
            short o8[8];
#pragma unroll
            for (int m = 0; m < 4; ++m) {
                o8[2*m]   = f2bf(ac[q * 4 + m].x);
                o8[2*m+1] = f2bf(ac[q * 4 + m].y);
            }
            *(int4*)&sA[row * LDA1 + 128 + cc * 32 + q * 8] = *(int4*)o8;
        }
    }
    __syncthreads();

    // Phase 3: MFMA base (K=256): wave w -> rows 16w..16w+15
    const int w = tid >> 6, l = tid & 63;
    f32x4 acc[8];
#pragma unroll
    for (int nt = 0; nt < 8; ++nt) acc[nt] = (f32x4)0.f;
    const int arow = w * 16 + (l & 15);
#pragma unroll
    for (int ks = 0; ks < 8; ++ks) {
        bf16x8 a = *(const bf16x8*)&sA[arow * LDA1 + ks * 32 + (l >> 4) * 8];
        const short* bp = (ks < 4) ? &Bp1e[((size_t)(ks * 8) * 64 + l) * 8]
                                   : &Bpw[((size_t)((ks - 4) * 8) * 64 + l) * 8];
#pragma unroll
        for (int nt = 0; nt < 8; ++nt) {
            bf16x8 bb = *(const bf16x8*)(bp + (size_t)nt * 64 * 8);
            acc[nt] = __builtin_amdgcn_mfma_f32_16x16x32_bf16(a, bb, acc[nt], 0, 0, 0);
        }
    }

    // Phase 4: base -> global, t1=tanh -> LDS (K=128 layout)
    short* t1l = (short*)(smem + T1OFF);
    const int r0 = w * 16 + (l >> 4) * 4;
    const int cl = l & 15;
#pragma unroll
    for (int nt = 0; nt < 8; ++nt) {
        const int col = nt * 16 + cl;
#pragma unroll
        for (int r = 0; r < 4; ++r) {
            const int grow = r0 + r;
            float v = acc[nt][r];
            baseh[(size_t)(gnode0 + grow) * D_ + col] = f2bf(v);
            t1l[grow * LDA2 + col] = f2bf(fast_tanh(v));
        }
    }
    __syncthreads();

    // Phase 5: MFMA u = t1 @ (enc2/16)
    f32x4 a2[8];
#pragma unroll
    for (int nt = 0; nt < 8; ++nt) a2[nt] = (f32x4)0.f;
#pragma unroll
    for (int ks = 0; ks < 4; ++ks) {
        bf16x8 a = *(const bf16x8*)&t1l[arow * LDA2 + ks * 32 + (l >> 4) * 8];
#pragma unroll
        for (int nt = 0; nt < 8; ++nt) {
            bf16x8 bb = *(const bf16x8*)&Bp2[((size_t)(ks * 8 + nt) * 64 + l) * 8];
            a2[nt] = __builtin_amdgcn_mfma_f32_16x16x32_bf16(a, bb, a2[nt], 0, 0, 0);
        }
    }
#pragma unroll
    for (int nt = 0; nt < 8; ++nt) {
        const int col = nt * 16 + cl;
#pragma unroll
        for (int r = 0; r < 4; ++r)
            u[(size_t)(gnode0 + r0 + r) * D_ + col] = f2bf(a2[nt][r]);
    }
}

// ---------------------------------------------------------------------------
// g2: stage u batch-slice in LDS; agg via LDS reads + pk_add;
//     t2 = tanh(base + agg); out[b] += (sum mask*t2) @ w2.
// ---------------------------------------------------------------------------
__global__ __launch_bounds__(512, 2) void g2(const int* __restrict__ nbr,
                                             const short* __restrict__ u,
                                             const short* __restrict__ baseh,
                                             const float* __restrict__ mask,
                                             const float* __restrict__ w2,
                                             float* __restrict__ out) {
    extern __shared__ char smem[];
    const int tid = threadIdx.x;
    const int logical = swz_blk();
    const int b = logical >> 2;
    const int node0 = (logical & 3) * 128;
    const int gnode0 = b * N_ + node0;

    // Phase 0: stage u (bf16 passthrough, swizzled)
    const short* uB = u + (size_t)b * N_ * D_;
#pragma unroll 4
    for (int it = 0; it < 16; ++it) {
        const int i = it * 4096 + tid * 8;
        int4 v = *(const int4*)&uB[i];
        *(int4*)(smem + s_addr(i >> 7, (i & 127) * 2)) = v;
    }
    __syncthreads();

    // Phase 1: agg
    const int row = tid >> 2, cc = tid & 3;
    int idxv[16];
#pragma unroll
    for (int q = 0; q < 4; ++q)
        *(int4*)&idxv[q * 4] = *(const int4*)&nbr[(size_t)(gnode0 + row) * 16 + q * 4];
    float2 ac[16];
#pragma unroll
    for (int q = 0; q < 16; ++q) { ac[q].x = 0.f; ac[q].y = 0.f; }
#pragma unroll
    for (int nb = 0; nb < 16; ++nb) {
        const int rr = idxv[nb];
        const int sbase = rr * 256 + cc * 64;
        const int sw = (rr & 7) << 4;
#pragma unroll
        for (int j = 0; j < 4; ++j) {
            int4 d = *(const int4*)(smem + ((sbase + j * 16) ^ sw));
            const unsigned* du = (const unsigned*)&d;
#pragma unroll
            for (int q = 0; q < 4; ++q) {
                pk_add(ac[j * 4 + q], bfbits2f(du[q] << 16), bfbits2f(du[q] & 0xffff0000u));
            }
        }
    }

    // Phase 2: t2 = tanh(base + agg), masked (into ac in place)
    const float mk = mask[gnode0 + row];
    {
        const short* br = &baseh[(size_t)(gnode0 + row) * D_ + cc * 32];
#pragma unroll
        for (int q = 0; q < 4; ++q) {
            int4 bv = *(const int4*)&br[q * 8];
            const short* bs = (const short*)&bv;
#pragma unroll
            for (int m = 0; m < 4; ++m) {
                ac[q * 4 + m].x = mk * fast_tanh(bf2f(bs[2*m])   + ac[q * 4 + m].x);
                ac[q * 4 + m].y = mk * fast_tanh(bf2f(bs[2*m+1]) + ac[q * 4 + m].y);
            }
        }
    }
    __syncthreads();   // staged u dead; predp overlays smem

    // Phase 3: reduce over rows (shfl over lane bits 2..5), predp per wave
    float* predp = (float*)smem;            // [8][128]
    float* ptot  = (float*)(smem + 4096);   // [128]
    const int w = tid >> 6, l = tid & 63;
#pragma unroll
    for (int q = 0; q < 16; ++q) {
#pragma unroll
        for (int st = 4; st <= 32; st <<= 1) {
            ac[q].x += __shfl_xor(ac[q].x, st);
            ac[q].y += __shfl_xor(ac[q].y, st);
        }
    }
    if (l < 4) {
#pragma unroll
        for (int q = 0; q < 4; ++q) {
#pragma unroll
            for (int m = 0; m < 4; ++m) {
                predp[w * 128 + l * 32 + q * 8 + m * 2]     = ac[q * 4 + m].x;
                predp[w * 128 + l * 32 + q * 8 + m * 2 + 1] = ac[q * 4 + m].y;
            }
        }
    }
    __syncthreads();
    if (tid < 128) {
        float tot = 0.f;
#pragma unroll
        for (int i = 0; i < 8; ++i) tot += predp[i * 128 + tid];
        ptot[tid] = tot;
    }
    __syncthreads();
    if (tid < 128) {
        float a2 = 0.f;
#pragma unroll 4
        for (int f = 0; f < 128; ++f) a2 += ptot[f] * w2[f * 128 + tid];
        atomicAdd(&out[b * 128 + tid], a2);
    }
}

extern "C" void kernel_launch(void* const* d_in, const int* in_sizes, int n_in,
                              void* d_out, int out_size, void* d_ws, size_t ws_size,
                              hipStream_t stream) {
    const float* word_embs   = (const float*)d_in[0];
    const int*   neibors     = (const int*)d_in[1];
    const float* lib_embs    = (const float*)d_in[2];
    const int*   neibors_lib = (const int*)d_in[3];
    const float* mask        = (const float*)d_in[4];
    const float* weight      = (const float*)d_in[5];
    const float* weight2     = (const float*)d_in[6];
    const float* enc_w1      = (const float*)d_in[7];
    const float* enc_w2      = (const float*)d_in[8];
    float* out = (float*)d_out;

    char* ws = (char*)d_ws;
    short* baseh = (short*)(ws);                        // 8 MB
    short* ubuf  = (short*)(ws + (1u << 23));           // 8 MB
    short* Bp1e  = (short*)(ws + (2u << 23));           // 32 KB
    short* Bpw   = (short*)(ws + (2u << 23) + 32768);   // 32 KB
    short* Bp2   = (short*)(ws + (2u << 23) + 65536);   // 32 KB

    hipFuncSetAttribute((const void*)g1, hipFuncAttributeMaxDynamicSharedMemorySize, 131072);
    hipFuncSetAttribute((const void*)g2, hipFuncAttributeMaxDynamicSharedMemorySize, 131072);

    pack<<<56, 256, 0, stream>>>(enc_w1, weight, enc_w2, Bp1e, Bpw, Bp2, out);
    g1<<<256, 512, 131072, stream>>>(word_embs, neibors_lib, lib_embs, Bp1e, Bpw, Bp2, baseh, ubuf);
    g2<<<256, 512, 131072, stream>>>(neibors, ubuf, baseh, mask, weight2, out);
}

// Round 14
// 48.331 us; speedup vs baseline: 1.1866x; 1.1534x over previous
//
#include <hip/hip_runtime.h>
#include <hip/hip_bf16.h>

#define B_   64
#define N_   512
#define D_   128
#define NPB  16                 // nodes per block
#define G1   ((B_*N_)/NPB)      // 2048 blocks

typedef float f32x4  __attribute__((ext_vector_type(4)));
typedef _Float16 f16x8 __attribute__((ext_vector_type(8)));

static __device__ __forceinline__ unsigned pkrtz(float x, float y) {
    return __builtin_bit_cast(unsigned, __builtin_amdgcn_cvt_pkrtz(x, y));
}
static __device__ __forceinline__ short f2h(float x) {
    _Float16 h = (_Float16)x;
    return __builtin_bit_cast(short, h);
}
static __device__ __forceinline__ float h2f(short s) {
    return (float)__builtin_bit_cast(_Float16, s);
}
// tanh(x) = 1 - 2/(e^{2x}+1); exact at +/-inf
static __device__ __forceinline__ float fast_tanh(float x) {
    float e = __expf(2.f * x);
    return 1.f - 2.f * __builtin_amdgcn_rcpf(e + 1.f);
}
// packed fp16x2 add, no unpack needed
static __device__ __forceinline__ void pk_add16(unsigned& acc, unsigned v) {
    asm("v_pk_add_f16 %0, %1, %0" : "+v"(acc) : "v"(v));
}

// ---------------------------------------------------------------------------
// prep: blocks 0..1023: lib fp32 -> fp16 (16 elems/thread)
//       blocks 1024..1055: pack Bp1 = [enc1 ; weight/16] (K=256, fp16 frags),
//                          Bp2 = enc2/16 (K=128); zero d_out.
// frag elem j of lane l, tile nt, step ks = M[ks*32+(l>>4)*8+j][nt*16+(l&15)]
// ---------------------------------------------------------------------------
__global__ __launch_bounds__(256) void prep(const float* __restrict__ lib,
                                            const float* __restrict__ enc1,
                                            const float* __restrict__ wgt,
                                            const float* __restrict__ enc2,
                                            short* __restrict__ libh,
                                            short* __restrict__ Bp1,
                                            short* __restrict__ Bp2,
                                            float* __restrict__ out) {
    const int blk = blockIdx.x;
    if (blk < 1024) {
        const size_t g = ((size_t)blk * 256 + threadIdx.x) * 16;
        unsigned o[8];
#pragma unroll
        for (int q = 0; q < 4; ++q) {
            float4 v = *(const float4*)&lib[g + q * 4];
            o[q * 2]     = pkrtz(v.x, v.y);
            o[q * 2 + 1] = pkrtz(v.z, v.w);
        }
        *(int4*)&libh[g]     = *(int4*)o;
        *(int4*)&libh[g + 8] = *(int4*)(o + 4);
        return;
    }
    int tid = (blk - 1024) * 256 + threadIdx.x;   // 0..8191
    out[tid] = 0.f;                               // B_*D_ = 8192
    short o8[8];
    if (tid < 4096) {
        int l = tid & 63, nt = (tid >> 6) & 7, ks = tid >> 9;   // ks 0..7
        int k0 = ks * 32 + (l >> 4) * 8;
        int col = nt * 16 + (l & 15);
#pragma unroll
        for (int j = 0; j < 8; ++j) {
            int r = k0 + j;
            float v = (r < 128) ? enc1[r * 128 + col] : wgt[(r - 128) * 128 + col] * 0.0625f;
            o8[j] = f2h(v);
        }
        *(int4*)&Bp1[(size_t)tid * 8] = *(int4*)o8;
    } else if (tid < 6144) {
        int t2 = tid - 4096;
        int l = t2 & 63, nt = (t2 >> 6) & 7, ks = t2 >> 9;      // ks 0..3
        int k0 = ks * 32 + (l >> 4) * 8;
        int col = nt * 16 + (l & 15);
#pragma unroll
        for (int j = 0; j < 8; ++j) o8[j] = f2h(enc2[(k0 + j) * 128 + col] * 0.0625f);
        *(int4*)&Bp2[(size_t)t2 * 8] = *(int4*)o8;
    }
}

// XCD-aware swizzle: 2048 blocks, 32 per batch. XCD k <- batches [8k,8k+8).
static __device__ __forceinline__ int swz_blk() {
    const int hw = blockIdx.x;
    return ((hw & 7) << 8) + (hw >> 3);
}

#define LDA1 264   // 256 + 8 pad (fp16 elems)
#define LDA2 136   // 128 + 8 pad

// ---------------------------------------------------------------------------
// gemm1: base = [word | sum_nb lib[idx]] @ [enc1 ; weight/16]  (K=256, f16 MFMA)
//        t1 = tanh(base).  Gather: 16 lanes/row, int4 loads, v_pk_add_f16.
// ---------------------------------------------------------------------------
__global__ __launch_bounds__(256) void gemm1(const float* __restrict__ word,
                                             const int* __restrict__ nbrL,
                                             const short* __restrict__ libh,
                                             const short* __restrict__ Bp1,
                                             short* __restrict__ baseh,
                                             short* __restrict__ t1) {
    __shared__ short sA[NPB * LDA1];
    __shared__ int sIdx[NPB * 16];
    const int tid = threadIdx.x;
    const int blk = swz_blk();
    const int b = blk >> 5;
    const int node0 = blk * NPB;

    if (tid < 64) *(int4*)&sIdx[tid * 4] = *(const int4*)&nbrL[(size_t)node0 * 16 + tid * 4];
    __syncthreads();

    const int row = tid >> 4;        // 0..15
    const int lg  = tid & 15;        // 8-col group

    // stage word row-part (fp32 -> fp16)
    {
        const float* wr = word + (size_t)(node0 + row) * D_ + lg * 8;
        float4 v0 = *(const float4*)&wr[0];
        float4 v1 = *(const float4*)&wr[4];
        unsigned o[4] = { pkrtz(v0.x, v0.y), pkrtz(v0.z, v0.w),
                          pkrtz(v1.x, v1.y), pkrtz(v1.z, v1.w) };
        *(int4*)&sA[row * LDA1 + lg * 8] = *(int4*)o;
    }

    // gather-sum neighbors: 16 x (1 lshl_add + 1 load_dwordx4 + 4 pk_add)
    {
        int idxr[16];
#pragma unroll
        for (int q = 0; q < 4; ++q) *(int4*)&idxr[q * 4] = *(const int4*)&sIdx[row * 16 + q * 4];
        const char* libB = (const char*)libh + (size_t)b * N_ * D_ * 2 + lg * 16;
        unsigned a0 = 0, a1 = 0, a2 = 0, a3 = 0;
#pragma unroll
        for (int nb = 0; nb < 16; ++nb) {
            int4 d = *(const int4*)(libB + ((unsigned)idxr[nb] << 8));
            pk_add16(a0, (unsigned)d.x);
            pk_add16(a1, (unsigned)d.y);
            pk_add16(a2, (unsigned)d.z);
            pk_add16(a3, (unsigned)d.w);
        }
        unsigned o[4] = { a0, a1, a2, a3 };   // raw sums; /16 folded into Bp1
        *(int4*)&sA[row * LDA1 + 128 + lg * 8] = *(int4*)o;
    }
    __syncthreads();

    // MFMA K=256: wave w -> col tiles 2w, 2w+1
    const int w = tid >> 6, l = tid & 63;
    f32x4 acc[2];
    acc[0] = (f32x4)0.f; acc[1] = (f32x4)0.f;
    const int arow = l & 15;
#pragma unroll
    for (int ks = 0; ks < 8; ++ks) {
        f16x8 a = *(const f16x8*)&sA[arow * LDA1 + ks * 32 + (l >> 4) * 8];
#pragma unroll
        for (int j = 0; j < 2; ++j) {
            const int nt = 2 * w + j;
            f16x8 bb = *(const f16x8*)&Bp1[((size_t)(ks * 8 + nt) * 64 + l) * 8];
            acc[j] = __builtin_amdgcn_mfma_f32_16x16x32_f16(a, bb, acc[j], 0, 0, 0);
        }
    }

    const int r0 = (l >> 4) * 4;
    const int cl = l & 15;
#pragma unroll
    for (int j = 0; j < 2; ++j) {
        const int col = (2 * w + j) * 16 + cl;
#pragma unroll
        for (int r = 0; r < 4; ++r) {
            size_t o = (size_t)(node0 + r0 + r) * D_ + col;
            float v = acc[j][r];
            baseh[o] = f2h(v);
            t1[o]    = f2h(fast_tanh(v));
        }
    }
}

// ---------------------------------------------------------------------------
// gemm2: t2 = tanh(base + (sum_nb t1[idx]) @ (enc2/16));
//        out[b] += (sum_n mask*t2) @ weight2
// ---------------------------------------------------------------------------
__global__ __launch_bounds__(256) void gemm2(const short* __restrict__ t1,
                                             const int* __restrict__ nbr,
                                             const short* __restrict__ Bp2,
                                             const short* __restrict__ baseh,
                                             const float* __restrict__ mask,
                                             const float* __restrict__ w2,
                                             float* __restrict__ out) {
    __shared__ short sA[NPB * LDA2];
    __shared__ int sIdx[NPB * 16];
    __shared__ float pred[128];
    __shared__ float smask[NPB];
    const int tid = threadIdx.x;
    const int blk = swz_blk();
    const int b = blk >> 5;
    const int node0 = blk * NPB;

    if (tid < 64) *(int4*)&sIdx[tid * 4] = *(const int4*)&nbr[(size_t)node0 * 16 + tid * 4];
    if (tid >= 64 && tid < 64 + NPB) smask[tid - 64] = mask[node0 + tid - 64];
    __syncthreads();

    const int row = tid >> 4;
    const int lg  = tid & 15;
    {
        int idxr[16];
#pragma unroll
        for (int q = 0; q < 4; ++q) *(int4*)&idxr[q * 4] = *(const int4*)&sIdx[row * 16 + q * 4];
        const char* tB = (const char*)t1 + (size_t)b * N_ * D_ * 2 + lg * 16;
        unsigned a0 = 0, a1 = 0, a2 = 0, a3 = 0;
#pragma unroll
        for (int nb = 0; nb < 16; ++nb) {
            int4 d = *(const int4*)(tB + ((unsigned)idxr[nb] << 8));
            pk_add16(a0, (unsigned)d.x);
            pk_add16(a1, (unsigned)d.y);
            pk_add16(a2, (unsigned)d.z);
            pk_add16(a3, (unsigned)d.w);
        }
        unsigned o[4] = { a0, a1, a2, a3 };   // /16 folded into Bp2
        *(int4*)&sA[row * LDA2 + lg * 8] = *(int4*)o;
    }
    __syncthreads();

    const int w = tid >> 6, l = tid & 63;
    f32x4 acc[2];
    acc[0] = (f32x4)0.f; acc[1] = (f32x4)0.f;
    const int arow = l & 15;
#pragma unroll
    for (int ks = 0; ks < 4; ++ks) {
        f16x8 a = *(const f16x8*)&sA[arow * LDA2 + ks * 32 + (l >> 4) * 8];
#pragma unroll
        for (int j = 0; j < 2; ++j) {
            const int nt = 2 * w + j;
            f16x8 bb = *(const f16x8*)&Bp2[((size_t)(ks * 8 + nt) * 64 + l) * 8];
            acc[j] = __builtin_amdgcn_mfma_f32_16x16x32_f16(a, bb, acc[j], 0, 0, 0);
        }
    }

    const int r0 = (l >> 4) * 4;
    const int cl = l & 15;
#pragma unroll
    for (int j = 0; j < 2; ++j) {
        const int col = (2 * w + j) * 16 + cl;
        float s = 0.f;
#pragma unroll
        for (int r = 0; r < 4; ++r) {
            size_t o = (size_t)(node0 + r0 + r) * D_ + col;
            float v = fast_tanh(h2f(baseh[o]) + acc[j][r]);
            s += v * smask[r0 + r];
        }
        s += __shfl_xor(s, 16);
        s += __shfl_xor(s, 32);
        if (l < 16) pred[col] = s;
    }
    __syncthreads();
    if (tid < 128) {
        float a2 = 0.f;
#pragma unroll 4
        for (int f = 0; f < 128; ++f) a2 += pred[f] * w2[f * 128 + tid];
        atomicAdd(&out[b * 128 + tid], a2);
    }
}

extern "C" void kernel_launch(void* const* d_in, const int* in_sizes, int n_in,
                              void* d_out, int out_size, void* d_ws, size_t ws_size,
                              hipStream_t stream) {
    const float* word_embs   = (const float*)d_in[0];
    const int*   neibors     = (const int*)d_in[1];
    const float* lib_embs    = (const float*)d_in[2];
    const int*   neibors_lib = (const int*)d_in[3];
    const float* mask        = (const float*)d_in[4];
    const float* weight      = (const float*)d_in[5];
    const float* weight2     = (const float*)d_in[6];
    const float* enc_w1      = (const float*)d_in[7];
    const float* enc_w2      = (const float*)d_in[8];
    float* out = (float*)d_out;

    char* ws = (char*)d_ws;
    short* baseh = (short*)(ws);                             // 8 MB fp16
    short* t1    = (short*)(ws + (1u << 23));                // 8 MB fp16
    short* libh  = (short*)(ws + (2u << 23));                // 8 MB fp16
    short* Bp1   = (short*)(ws + (3u << 23));                // 64 KB
    short* Bp2   = (short*)(ws + (3u << 23) + 65536);        // 32 KB

    prep<<<1056, 256, 0, stream>>>(lib_embs, enc_w1, weight, enc_w2, libh, Bp1, Bp2, out);
    gemm1<<<G1, 256, 0, stream>>>(word_embs, neibors_lib, libh, Bp1, baseh, t1);
    gemm2<<<G1, 256, 0, stream>>>(t1, neibors, Bp2, baseh, mask, weight2, out);
}